// Round 2
// baseline (1031.642 us; speedup 1.0000x reference)
//
#include <hip/hip_runtime.h>
#include <math.h>

// KAN activation: out = wb * silu(x) + ws * BSpline(knots, coeffs, k=3)(x)
// n_active = 10-3-1 = 6 coeffs; interval i = clip(searchsorted-1, 3, 5) ->
// exactly three de Boor variants, fully branchless via selects.
//
// Streaming structure: block-contiguous chunks (1024 float4 per block),
// 4 independent float4 loads in flight per thread, nontemporal stores.

typedef float f4 __attribute__((ext_vector_type(4)));

__global__ __launch_bounds__(256) void kan_kernel(
    const float* __restrict__ xin,
    const float* __restrict__ knots,
    const float* __restrict__ coeffs,
    const float* __restrict__ wbp,
    const float* __restrict__ wsp,
    float* __restrict__ out,
    unsigned n4, unsigned n)
{
    // ---- uniform preloads (scalar loads; uniform addresses) ----
    const float t1 = knots[1], t2 = knots[2], t3 = knots[3], t4 = knots[4];
    const float t5 = knots[5], t6 = knots[6], t7 = knots[7], t8 = knots[8];
    const float c0 = coeffs[0], c1 = coeffs[1], c2 = coeffs[2];
    const float c3 = coeffs[3], c4 = coeffs[4], c5 = coeffs[5];
    const float wb = wbp[0], ws = wsp[0];

    // 12 distinct inverse denominators (exact div once per thread, amortized
    // over 16 evals). inv3_k = 1/(t[k+3]-t[k]), inv2_k = 1/(t[k+2]-t[k]),
    // inv1_k = 1/(t[k+1]-t[k]).
    const float inv3_1 = 1.0f / (t4 - t1), inv3_2 = 1.0f / (t5 - t2);
    const float inv3_3 = 1.0f / (t6 - t3), inv3_4 = 1.0f / (t7 - t4);
    const float inv3_5 = 1.0f / (t8 - t5);
    const float inv2_2 = 1.0f / (t4 - t2), inv2_3 = 1.0f / (t5 - t3);
    const float inv2_4 = 1.0f / (t6 - t4), inv2_5 = 1.0f / (t7 - t5);
    const float inv1_3 = 1.0f / (t4 - t3), inv1_4 = 1.0f / (t5 - t4);
    const float inv1_5 = 1.0f / (t6 - t5);

    auto eval = [&](float x) -> float {
        const bool ge4 = (x >= t4);   // i >= 4
        const bool ge5 = (x >= t5);   // i == 5
#define KAN_SEL(a, b, c) (ge4 ? (ge5 ? (c) : (b)) : (a))
        float d0 = KAN_SEL(c0, c1, c2);
        float d1 = KAN_SEL(c1, c2, c3);
        float d2 = KAN_SEL(c2, c3, c4);
        float d3 = KAN_SEL(c3, c4, c5);
        const float ti   = KAN_SEL(t3, t4, t5);   // t[i]
        const float tim1 = KAN_SEL(t2, t3, t4);   // t[i-1]
        const float tim2 = KAN_SEL(t1, t2, t3);   // t[i-2]
        const float i13 = KAN_SEL(inv3_3, inv3_4, inv3_5);  // r1 j=3: inv3_i
        const float i12 = KAN_SEL(inv3_2, inv3_3, inv3_4);  // r1 j=2: inv3_{i-1}
        const float i11 = KAN_SEL(inv3_1, inv3_2, inv3_3);  // r1 j=1: inv3_{i-2}
        const float i23 = KAN_SEL(inv2_3, inv2_4, inv2_5);  // r2 j=3: inv2_i
        const float i22 = KAN_SEL(inv2_2, inv2_3, inv2_4);  // r2 j=2: inv2_{i-1}
        const float i33 = KAN_SEL(inv1_3, inv1_4, inv1_5);  // r3 j=3: inv1_i
#undef KAN_SEL
        const float u0 = x - ti;
        const float u1 = x - tim1;
        const float u2 = x - tim2;
        float a;
        a = u0 * i13; d3 = fmaf(a, d3 - d2, d2);
        a = u1 * i12; d2 = fmaf(a, d2 - d1, d1);
        a = u2 * i11; d1 = fmaf(a, d1 - d0, d0);
        a = u0 * i23; d3 = fmaf(a, d3 - d2, d2);
        a = u1 * i22; d2 = fmaf(a, d2 - d1, d1);
        a = u0 * i33; d3 = fmaf(a, d3 - d2, d2);
        // silu(x) = x / (1 + exp(-x)) via hw exp + hw rcp
        const float e = __expf(-x);
        const float b = x * __builtin_amdgcn_rcpf(1.0f + e);
        return fmaf(wb, b, ws * d3);
    };

    const f4* __restrict__ x4 = (const f4*)xin;
    f4* __restrict__ o4 = (f4*)out;

    // Block-contiguous: block b owns float4s [b*1024, b*1024+1024).
    const unsigned base = blockIdx.x * 1024u + threadIdx.x;
    const unsigned i0 = base, i1 = base + 256u, i2 = base + 512u, i3 = base + 768u;

    // Issue all 4 loads before any compute (MLP=4).
    f4 xv0, xv1, xv2, xv3;
    const bool v0 = i0 < n4, v1 = i1 < n4, v2 = i2 < n4, v3 = i3 < n4;
    if (v0) xv0 = x4[i0];
    if (v1) xv1 = x4[i1];
    if (v2) xv2 = x4[i2];
    if (v3) xv3 = x4[i3];

#define KAN_DO(v, xv, idx)                                                  \
    if (v) {                                                                \
        f4 ov;                                                              \
        ov.x = eval(xv.x); ov.y = eval(xv.y);                               \
        ov.z = eval(xv.z); ov.w = eval(xv.w);                               \
        __builtin_nontemporal_store(ov, &o4[idx]);                          \
    }
    KAN_DO(v0, xv0, i0)
    KAN_DO(v1, xv1, i1)
    KAN_DO(v2, xv2, i2)
    KAN_DO(v3, xv3, i3)
#undef KAN_DO

    // Scalar tail (n % 4 != 0) — not hit for this shape, kept for generality.
    if (blockIdx.x == 0 && threadIdx.x < (n & 3u)) {
        const unsigned j = (n4 << 2) + threadIdx.x;
        out[j] = eval(xin[j]);
    }
}

extern "C" void kernel_launch(void* const* d_in, const int* in_sizes, int n_in,
                              void* d_out, int out_size, void* d_ws, size_t ws_size,
                              hipStream_t stream) {
    const float* x      = (const float*)d_in[0];
    const float* knots  = (const float*)d_in[1];
    const float* coeffs = (const float*)d_in[2];
    const float* wb     = (const float*)d_in[3];
    const float* ws     = (const float*)d_in[4];
    float* out = (float*)d_out;

    const unsigned n  = (unsigned)out_size;
    const unsigned n4 = n >> 2;
    const unsigned per_block = 1024;  // float4s per block (256 thr x 4)
    const unsigned grid = (n4 + per_block - 1) / per_block;  // 8192 at n=33.5M
    kan_kernel<<<grid, 256, 0, stream>>>(x, knots, coeffs, wb, ws, out, n4, n);
}

// Round 3
// 1000.357 us; speedup vs baseline: 1.0313x; 1.0313x over previous
//
#include <hip/hip_runtime.h>
#include <math.h>

// KAN activation: out = wb * silu(x) + ws * BSpline(knots, coeffs, k=3)(x)
// n_active = 10-3-1 = 6 coeffs; interval i = clip(searchsorted-1, 3, 5) ->
// exactly three de Boor variants, fully branchless via selects.
//
// Access structure (round 3): LANE-BLOCKED 64B — each thread owns 16
// consecutive floats (4 consecutive float4 = one full 64B line per lane).
// Wave covers 4KB contiguous, block covers 16KB contiguous. This makes
// per-lane traffic exactly line-granular, discriminating (and fixing, if
// true) the hypothesis that lane-interleaved 16B accesses are serviced at
// >=256B granules (FETCH_SIZE showed 18-26x read amplification in r1/r2).
// Regular (cached) loads and stores — nontemporal stores doubled WRITE_SIZE
// in round 2, reverted.

typedef float f4 __attribute__((ext_vector_type(4)));

__global__ __launch_bounds__(256) void kan_kernel(
    const float* __restrict__ xin,
    const float* __restrict__ knots,
    const float* __restrict__ coeffs,
    const float* __restrict__ wbp,
    const float* __restrict__ wsp,
    float* __restrict__ out,
    unsigned n4)
{
    // ---- uniform preloads (scalar loads; uniform addresses) ----
    const float t1 = knots[1], t2 = knots[2], t3 = knots[3], t4 = knots[4];
    const float t5 = knots[5], t6 = knots[6], t7 = knots[7], t8 = knots[8];
    const float c0 = coeffs[0], c1 = coeffs[1], c2 = coeffs[2];
    const float c3 = coeffs[3], c4 = coeffs[4], c5 = coeffs[5];
    const float wb = wbp[0], ws = wsp[0];

    // 12 distinct inverse denominators, hoisted (exact div, once per thread).
    const float inv3_1 = 1.0f / (t4 - t1), inv3_2 = 1.0f / (t5 - t2);
    const float inv3_3 = 1.0f / (t6 - t3), inv3_4 = 1.0f / (t7 - t4);
    const float inv3_5 = 1.0f / (t8 - t5);
    const float inv2_2 = 1.0f / (t4 - t2), inv2_3 = 1.0f / (t5 - t3);
    const float inv2_4 = 1.0f / (t6 - t4), inv2_5 = 1.0f / (t7 - t5);
    const float inv1_3 = 1.0f / (t4 - t3), inv1_4 = 1.0f / (t5 - t4);
    const float inv1_5 = 1.0f / (t6 - t5);

    auto eval = [&](float x) -> float {
        const bool ge4 = (x >= t4);   // i >= 4
        const bool ge5 = (x >= t5);   // i == 5
#define KAN_SEL(a, b, c) (ge4 ? (ge5 ? (c) : (b)) : (a))
        float d0 = KAN_SEL(c0, c1, c2);
        float d1 = KAN_SEL(c1, c2, c3);
        float d2 = KAN_SEL(c2, c3, c4);
        float d3 = KAN_SEL(c3, c4, c5);
        const float ti   = KAN_SEL(t3, t4, t5);   // t[i]
        const float tim1 = KAN_SEL(t2, t3, t4);   // t[i-1]
        const float tim2 = KAN_SEL(t1, t2, t3);   // t[i-2]
        const float i13 = KAN_SEL(inv3_3, inv3_4, inv3_5);
        const float i12 = KAN_SEL(inv3_2, inv3_3, inv3_4);
        const float i11 = KAN_SEL(inv3_1, inv3_2, inv3_3);
        const float i23 = KAN_SEL(inv2_3, inv2_4, inv2_5);
        const float i22 = KAN_SEL(inv2_2, inv2_3, inv2_4);
        const float i33 = KAN_SEL(inv1_3, inv1_4, inv1_5);
#undef KAN_SEL
        const float u0 = x - ti;
        const float u1 = x - tim1;
        const float u2 = x - tim2;
        float a;
        a = u0 * i13; d3 = fmaf(a, d3 - d2, d2);
        a = u1 * i12; d2 = fmaf(a, d2 - d1, d1);
        a = u2 * i11; d1 = fmaf(a, d1 - d0, d0);
        a = u0 * i23; d3 = fmaf(a, d3 - d2, d2);
        a = u1 * i22; d2 = fmaf(a, d2 - d1, d1);
        a = u0 * i33; d3 = fmaf(a, d3 - d2, d2);
        const float e = __expf(-x);
        const float b = x * __builtin_amdgcn_rcpf(1.0f + e);
        return fmaf(wb, b, ws * d3);
    };

    const f4* __restrict__ x4 = (const f4*)xin;
    f4* __restrict__ o4 = (f4*)out;

    // XCD-contiguous chunking: blocks on the same XCD cover a contiguous
    // region (bijective since grid % 8 == 0; identity fallback otherwise).
    unsigned bid = blockIdx.x;
    const unsigned nblk = gridDim.x;
    if ((nblk & 7u) == 0u) {
        const unsigned per = nblk >> 3;
        bid = (bid & 7u) * per + (bid >> 3);
    }

    // Thread owns float4 indices [base, base+4) — 64 contiguous bytes.
    const unsigned base = (bid * 256u + threadIdx.x) * 4u;

    f4 xv0, xv1, xv2, xv3;
    const bool v0 = base + 0u < n4, v1 = base + 1u < n4;
    const bool v2 = base + 2u < n4, v3 = base + 3u < n4;
    if (v0) xv0 = x4[base + 0u];
    if (v1) xv1 = x4[base + 1u];
    if (v2) xv2 = x4[base + 2u];
    if (v3) xv3 = x4[base + 3u];

#define KAN_DO(v, xv, idx)                                                  \
    if (v) {                                                                \
        f4 ov;                                                              \
        ov.x = eval(xv.x); ov.y = eval(xv.y);                               \
        ov.z = eval(xv.z); ov.w = eval(xv.w);                               \
        o4[idx] = ov;                                                       \
    }
    KAN_DO(v0, xv0, base + 0u)
    KAN_DO(v1, xv1, base + 1u)
    KAN_DO(v2, xv2, base + 2u)
    KAN_DO(v3, xv3, base + 3u)
#undef KAN_DO
}

__global__ void kan_tail(const float* __restrict__ xin,
                         const float* __restrict__ knots,
                         const float* __restrict__ coeffs,
                         const float* __restrict__ wbp,
                         const float* __restrict__ wsp,
                         float* __restrict__ out,
                         unsigned start, unsigned n)
{
    // Scalar tail for n % 4 != 0 (not hit for this shape).
    const unsigned j = start + blockIdx.x * blockDim.x + threadIdx.x;
    if (j >= n) return;
    const float x = xin[j];
    const float t4 = knots[4], t5 = knots[5];
    // minimal correct path: recompute via generic de Boor (rarely executed)
    float t[10], c[6];
    for (int q = 0; q < 10; ++q) t[q] = knots[q];
    for (int q = 0; q < 6; ++q) c[q] = coeffs[q];
    int i = 3 + (x >= t4 ? 1 : 0) + (x >= t5 ? 1 : 0);
    float d[4];
    for (int q = 0; q <= 3; ++q) d[q] = c[i - 3 + q];
    for (int r = 1; r <= 3; ++r)
        for (int q = 3; q >= r; --q) {
            const float tlo = t[i + q - 3], thi = t[i + q + 1 - r];
            const float al = (x - tlo) / (thi - tlo);
            d[q] = (1.0f - al) * d[q - 1] + al * d[q];
        }
    const float b = x / (1.0f + __expf(-x));
    out[j] = wbp[0] * b + wsp[0] * d[3];
}

extern "C" void kernel_launch(void* const* d_in, const int* in_sizes, int n_in,
                              void* d_out, int out_size, void* d_ws, size_t ws_size,
                              hipStream_t stream) {
    const float* x      = (const float*)d_in[0];
    const float* knots  = (const float*)d_in[1];
    const float* coeffs = (const float*)d_in[2];
    const float* wb     = (const float*)d_in[3];
    const float* ws     = (const float*)d_in[4];
    float* out = (float*)d_out;

    const unsigned n  = (unsigned)out_size;
    const unsigned n4 = n >> 2;
    const unsigned per_block = 256u * 4u;  // float4s per block
    const unsigned grid = (n4 + per_block - 1u) / per_block;  // 8192 at n=2^25
    kan_kernel<<<grid, 256, 0, stream>>>(x, knots, coeffs, wb, ws, out, n4);
    const unsigned rem = n & 3u;
    if (rem) {
        kan_tail<<<1, 64, 0, stream>>>(x, knots, coeffs, wb, ws, out, n - rem, n);
    }
}